// Round 17
// baseline (407.150 us; speedup 1.0000x reference)
//
#include <hip/hip_runtime.h>

typedef short short8 __attribute__((ext_vector_type(8)));
typedef short short4v __attribute__((ext_vector_type(4)));
typedef float floatx4 __attribute__((ext_vector_type(4)));
typedef unsigned short ushort_t;
typedef unsigned int uint_t;

#define DI __device__ __forceinline__

DI ushort_t f2bf(float f) {
  uint_t u = __builtin_bit_cast(uint_t, f);
  uint_t r = u + 0x7FFFu + ((u >> 16) & 1u);
  return (ushort_t)(r >> 16);
}

DI float exp2a(float x) {            // v_exp_f32 IS 2^x on AMD
  float r;
  asm("v_exp_f32 %0, %1" : "=v"(r) : "v"(x));
  return r;
}

DI floatx4 mfma16(short8 a, short8 b, floatx4 c) {
  return __builtin_amdgcn_mfma_f32_16x16x32_bf16(a, b, c, 0, 0, 0);
}

DI void async16(const void* g, void* l) {
  __builtin_amdgcn_global_load_lds(
      (__attribute__((address_space(1))) void*)(g),
      (__attribute__((address_space(3))) void*)(l), 16, 0, 0);
}

DI void cfence() { asm volatile("" ::: "memory"); }

// ---------------- fused f32 -> bf16 conversion (4 segments, 1 launch) ----------------
__global__ __launch_bounds__(256)
void k_f2bf4(const float* __restrict__ x, const float* __restrict__ wq,
             const float* __restrict__ wkv, const float* __restrict__ wo,
             ushort_t* __restrict__ xb, ushort_t* __restrict__ wqb,
             ushort_t* __restrict__ wkvb, ushort_t* __restrict__ wob)
{
  const int blk = blockIdx.x;
  const float* in; ushort_t* out; long base;
  if (blk < 8192)       { in = x;   out = xb;   base = (long)blk * 2048; }
  else if (blk < 10240) { in = wq;  out = wqb;  base = (long)(blk - 8192) * 2048; }
  else if (blk < 11264) { in = wkv; out = wkvb; base = (long)(blk - 10240) * 2048; }
  else                  { in = wo;  out = wob;  base = (long)(blk - 11264) * 2048; }
  const long i = base + (long)threadIdx.x * 8;
  const float4 a = *(const float4*)(in + i);
  const float4 b = *(const float4*)(in + i + 4);
  union { short8 s; ushort_t u[8]; } o;
  o.u[0] = f2bf(a.x); o.u[1] = f2bf(a.y); o.u[2] = f2bf(a.z); o.u[3] = f2bf(a.w);
  o.u[4] = f2bf(b.x); o.u[5] = f2bf(b.y); o.u[6] = f2bf(b.z); o.u[7] = f2bf(b.w);
  *(short8*)(out + i) = o.s;
}

// ======== 128x128 quad-buffered KV GEMM + fused V-transpose epilogue (r13-proven) ========
__global__ __launch_bounds__(256)
void k_gemmkv(const ushort_t* __restrict__ A, const ushort_t* __restrict__ B,
              const float* __restrict__ bias, ushort_t* __restrict__ KVout,
              ushort_t* __restrict__ Vt, int N, int K)
{
  __shared__ __align__(16) ushort_t As[4][128 * 32];
  __shared__ __align__(16) ushort_t Bs[4][128 * 32];
  const int tid = threadIdx.x;
  const int w = tid >> 6, l = tid & 63;
  const int wm = w >> 1, wn = w & 1;
  const int lr = l & 15, lg = l >> 4;
  const long m0 = (long)blockIdx.y * 128;
  const long n0 = (long)blockIdx.x * 128;

  const floatx4 fz = {0.f, 0.f, 0.f, 0.f};
  floatx4 acc[4][4];
#pragma unroll
  for (int i = 0; i < 4; ++i)
#pragma unroll
    for (int j = 0; j < 4; ++j) acc[i][j] = fz;

  const int c0 = tid, c1 = 256 + tid;
  const int r0 = c0 >> 2, r1 = c1 >> 2;
  const ushort_t* gA0 = A + (m0 + r0) * K + (((c0 & 3) ^ (r0 & 3)) << 3);
  const ushort_t* gA1 = A + (m0 + r1) * K + (((c1 & 3) ^ (r1 & 3)) << 3);
  const ushort_t* gB0 = B + (n0 + r0) * K + (((c0 & 3) ^ (r0 & 3)) << 3);
  const ushort_t* gB1 = B + (n0 + r1) * K + (((c1 & 3) ^ (r1 & 3)) << 3);

  const int nK = K >> 5;
#pragma unroll
  for (int pt = 0; pt < 3; ++pt) {
    const int ko = pt << 5;
    async16(gA0 + ko, &As[pt][c0 * 8]);
    async16(gA1 + ko, &As[pt][c1 * 8]);
    async16(gB0 + ko, &Bs[pt][c0 * 8]);
    async16(gB1 + ko, &Bs[pt][c1 * 8]);
  }

  const int xg = (lr & 3);

  for (int kt = 0; kt < nK; ++kt) {
    const int cur = kt & 3;
    const int rem = nK - 1 - kt;
    if (rem >= 3) {
      const int ko = (kt + 3) << 5;
      const int nb = (kt + 3) & 3;
      async16(gA0 + ko, &As[nb][c0 * 8]);
      async16(gA1 + ko, &As[nb][c1 * 8]);
      async16(gB0 + ko, &Bs[nb][c0 * 8]);
      async16(gB1 + ko, &Bs[nb][c1 * 8]);
      asm volatile("s_waitcnt vmcnt(12)" ::: "memory");
    } else if (rem == 2) {
      asm volatile("s_waitcnt vmcnt(8)" ::: "memory");
    } else if (rem == 1) {
      asm volatile("s_waitcnt vmcnt(4)" ::: "memory");
    } else {
      asm volatile("s_waitcnt vmcnt(0)" ::: "memory");
    }
    __builtin_amdgcn_s_barrier();
    cfence();

    short8 a[4], b[4];
#pragma unroll
    for (int i = 0; i < 4; ++i)
      a[i] = *(const short8*)&As[cur][(wm * 64 + i * 16 + lr) * 32 + ((lg ^ xg) * 8)];
#pragma unroll
    for (int j = 0; j < 4; ++j)
      b[j] = *(const short8*)&Bs[cur][(wn * 64 + j * 16 + lr) * 32 + ((lg ^ xg) * 8)];
#pragma unroll
    for (int i = 0; i < 4; ++i)
#pragma unroll
      for (int j = 0; j < 4; ++j)
        acc[i][j] = mfma16(a[i], b[j], acc[i][j]);

    asm volatile("s_waitcnt lgkmcnt(0)" ::: "memory");
    __builtin_amdgcn_s_barrier();
    cfence();
  }

#pragma unroll
  for (int j = 0; j < 4; ++j) {
    const long gn = n0 + wn * 64 + j * 16 + lr;
    const float bv = bias[gn];
    const int isV = (int)((gn >> 7) & 1);
    const long vrowB = (long)((gn >> 8) * 128 + (gn & 127)) * 1024;
#pragma unroll
    for (int i = 0; i < 4; ++i) {
      const long gm = m0 + wm * 64 + i * 16 + lg * 4;
#pragma unroll
      for (int r = 0; r < 4; ++r) {
        const ushort_t ov = f2bf(acc[i][j][r] + bv);
        const long gmr = gm + r;
        if (isV) Vt[((gmr >> 10) * 512) * 1024 + vrowB + (gmr & 1023)] = ov;
        else     KVout[gmr * 1024 + gn] = ov;
      }
    }
  }
}

// ======== 256x256 GEMM, 16 waves, 4 waves/SIMD (r16, best measured) — Q and O ========
template<int OUT_BF16>
__global__ __launch_bounds__(1024, 4)
void k_gemm4(const ushort_t* __restrict__ A, const ushort_t* __restrict__ B,
             const float* __restrict__ bias, void* __restrict__ Cout,
             int N, int K, int gx, float out_scale)
{
  __shared__ __align__(16) ushort_t Al[2][256 * 64];
  __shared__ __align__(16) ushort_t Bl[2][256 * 64];
  const int tid = threadIdx.x;
  const int w = tid >> 6, l = tid & 63;
  const int wrow = w >> 2, wcol = w & 3;
  const int lr = l & 15, lg = l >> 4;

  const int nwg = gridDim.x;
  const int qd = nwg >> 3;
  const int p = blockIdx.x;
  const int swz = (p & 7) * qd + (p >> 3);
  const long m0 = (long)(swz / gx) * 256;
  const long n0 = (long)(swz % gx) * 256;

  const floatx4 fz = {0.f, 0.f, 0.f, 0.f};
  floatx4 acc[4][4];
#pragma unroll
  for (int i = 0; i < 4; ++i)
#pragma unroll
    for (int j = 0; j < 4; ++j) acc[i][j] = fz;

  const int cA0 = tid, cA1 = 1024 + tid;
  const int rA0 = cA0 >> 3, rA1 = cA1 >> 3;
  const ushort_t* aS0 = A + (m0 + rA0) * K + (((cA0 & 7) ^ (rA0 & 7)) << 3);
  const ushort_t* aS1 = A + (m0 + rA1) * K + (((cA1 & 7) ^ (rA1 & 7)) << 3);
  const ushort_t* bS0 = B + (n0 + rA0) * K + (((cA0 & 7) ^ (rA0 & 7)) << 3);
  const ushort_t* bS1 = B + (n0 + rA1) * K + (((cA1 & 7) ^ (rA1 & 7)) << 3);
  const int d0 = cA0 * 8, d1 = cA1 * 8;

  const int x8 = lr & 7;
  const int g0 = (lg ^ x8) * 8;
  const int g1 = ((4 + lg) ^ x8) * 8;
  const int raB = (wrow * 64 + lr) * 64;
  const int rbB = (wcol * 64 + lr) * 64;

  const int nT = K >> 6;
  async16(aS0, &Al[0][d0]);
  async16(aS1, &Al[0][d1]);
  async16(bS0, &Bl[0][d0]);
  async16(bS1, &Bl[0][d1]);

  for (int t = 0; t < nT; ++t) {
    const int cur = t & 1;
    asm volatile("s_waitcnt vmcnt(0) lgkmcnt(0)" ::: "memory");
    __builtin_amdgcn_s_barrier();
    cfence();
    if (t + 1 < nT) {
      const int ko = (t + 1) << 6;
      async16(aS0 + ko, &Al[cur ^ 1][d0]);
      async16(aS1 + ko, &Al[cur ^ 1][d1]);
      async16(bS0 + ko, &Bl[cur ^ 1][d0]);
      async16(bS1 + ko, &Bl[cur ^ 1][d1]);
    }
    short8 a[4], b[4];
#pragma unroll
    for (int i = 0; i < 4; ++i)
      a[i] = *(const short8*)&Al[cur][raB + i * 1024 + g0];
#pragma unroll
    for (int j = 0; j < 4; ++j)
      b[j] = *(const short8*)&Bl[cur][rbB + j * 1024 + g0];
    __builtin_amdgcn_s_setprio(1);
#pragma unroll
    for (int i = 0; i < 4; ++i)
#pragma unroll
      for (int j = 0; j < 4; ++j)
        acc[i][j] = mfma16(a[i], b[j], acc[i][j]);
    __builtin_amdgcn_s_setprio(0);
#pragma unroll
    for (int i = 0; i < 4; ++i)
      a[i] = *(const short8*)&Al[cur][raB + i * 1024 + g1];
#pragma unroll
    for (int j = 0; j < 4; ++j)
      b[j] = *(const short8*)&Bl[cur][rbB + j * 1024 + g1];
    __builtin_amdgcn_s_setprio(1);
#pragma unroll
    for (int i = 0; i < 4; ++i)
#pragma unroll
      for (int j = 0; j < 4; ++j)
        acc[i][j] = mfma16(a[i], b[j], acc[i][j]);
    __builtin_amdgcn_s_setprio(0);
    cfence();
  }

#pragma unroll
  for (int j = 0; j < 4; ++j) {
    const long gn = n0 + wcol * 64 + j * 16 + lr;
    const float bv = bias[gn];
#pragma unroll
    for (int i = 0; i < 4; ++i) {
      const long gm = m0 + wrow * 64 + i * 16 + lg * 4;
#pragma unroll
      for (int r = 0; r < 4; ++r) {
        const float v = (acc[i][j][r] + bv) * out_scale;
        if (OUT_BF16) ((ushort_t*)Cout)[(gm + r) * N + gn] = f2bf(v);
        else          ((float*)Cout)[(gm + r) * N + gn] = v;
      }
    }
  }
}

// ---------------- Flash attention (causal, GQA) — V read direct from L2 ----------------
// r15 structure, but V is NOT LDS-staged (m169 lesson: per-(b,kh) V = 256KB is
// L2-resident and shared by 64 blocks; staging it was pure overhead). LDS drops
// 74.75K -> 41.2K => 3 blocks/CU (12 waves, +50% TLP on the binding VALU pipe).
// PV reads vf directly from Vt ([d][t] layout): 16B/lane, 64B-contiguous rows.
// Sync unchanged: single barrier/tile governs K dbuf + P; V loads are register-
// consumed (compiler vmcnt) and drained by the next tile-top vmcnt(0) anyway.
__global__ __launch_bounds__(256)
void k_attn(const ushort_t* __restrict__ Q, const ushort_t* __restrict__ KV,
            const ushort_t* __restrict__ Vt, ushort_t* __restrict__ Y)
{
  __shared__ __align__(16) ushort_t Kl[2][64 * 128];   // 32 KB
  __shared__ __align__(16) ushort_t Pl[4][16][72];     // 9.2 KB
  const int tid = threadIdx.x;
  const int w = tid >> 6, l = tid & 63;
  const int lr = l & 15, lg = l >> 4;
  const int p = blockIdx.x;
  const int v = ((p & 7) << 8) | (p >> 3);
  const int b = v >> 8;
  const int kh = (v >> 6) & 3;
  const int hs = (v >> 4) & 3;
  const int qt = 15 - (v & 15);
  const int h = kh * 4 + hs;
  const int qrow = qt * 64 + w * 16;

  const ushort_t* qptr = Q + ((long)(b * 1024 + qrow + lr)) * 2048 + h * 128 + lg * 8;
  short8 qf[4];
#pragma unroll
  for (int c = 0; c < 4; ++c) qf[c] = *(const short8*)(qptr + c * 32);

  // K staging (pre-swizzled source granules, linear LDS dest)
  const ushort_t* kg[4];
  int ld[4];
#pragma unroll
  for (int i = 0; i < 4; ++i) {
    const int c = i * 256 + tid;
    const int row = c >> 4, sgk = (c & 15) ^ (row & 7);
    kg[i] = KV + ((long)(b * 1024 + row)) * 1024 + kh * 256 + sgk * 8;
    ld[i] = c * 8;
  }
  // per-lane V global base: row d = dt*16+lr, col granule lg*8
  const ushort_t* vgp = Vt + ((long)((b * 4 + kh) * 128 + lr)) * 1024 + lg * 8;

  float m_s = 0.f;          // reference max (0-init safe: defer-max bounds P by 2^8)
  float l_p = 0.f;          // per-lane partial denominator
  const floatx4 fz = {0.f, 0.f, 0.f, 0.f};
  floatx4 yacc[8];
#pragma unroll
  for (int dt = 0; dt < 8; ++dt) yacc[dt] = fz;

  const int xk = (lr & 7) << 4;

#pragma unroll
  for (int i = 0; i < 4; ++i) async16(kg[i], &Kl[0][ld[i]]);

  for (int t = 0; t <= qt; ++t) {
    const ushort_t* KlC = &Kl[t & 1][0];
    // drain my K(t) DMAs (issued a full tile ago) + V reg-loads + my t-1 DS ops
    asm volatile("s_waitcnt vmcnt(0) lgkmcnt(0)" ::: "memory");
    __builtin_amdgcn_s_barrier();   // K(t) ready for all; t-1 readers done
    cfence();
    if (t < qt) {                    // stage K(t+1) into the other buffer
      const long ko = (long)(t + 1) * 65536;
      ushort_t* KlN = &Kl[(t + 1) & 1][0];
#pragma unroll
      for (int i = 0; i < 4; ++i) async16(kg[i] + ko, &KlN[ld[i]]);
    }

    const floatx4 finit = {-m_s, -m_s, -m_s, -m_s};
    floatx4 st[4];
#pragma unroll
    for (int k2 = 0; k2 < 4; ++k2) {
      floatx4 sacc = finit;
      const int row = k2 * 16 + lr;
#pragma unroll
      for (int c = 0; c < 4; ++c) {
        const int off = row * 256 + ((c * 64 + lg * 16) ^ xk);
        const short8 kf = *(const short8*)((const char*)KlC + off);
        sacc = mfma16(kf, qf[c], sacc);
      }
      st[k2] = sacc;
    }
    if (t == qt) {
      const int qg = qrow + lr;
#pragma unroll
      for (int k2 = 0; k2 < 4; ++k2)
#pragma unroll
        for (int r = 0; r < 4; ++r)
          if (t * 64 + k2 * 16 + lg * 4 + r > qg) st[k2][r] = -__builtin_inff();
    }
    float pm = -__builtin_inff();
#pragma unroll
    for (int k2 = 0; k2 < 4; ++k2)
      pm = fmaxf(pm, fmaxf(fmaxf(st[k2][0], st[k2][1]), fmaxf(st[k2][2], st[k2][3])));
    if (!__all(pm <= 8.f)) {
      float pmf = fmaxf(pm, __shfl_xor(pm, 16));
      pmf = fmaxf(pmf, __shfl_xor(pmf, 32));
      const float d = fmaxf(pmf, 0.f);
      m_s += d;
      const float corr = exp2a(-d);
      l_p *= corr;
      const float cc0 = __shfl(corr, lg * 4 + 0);
      const float cc1 = __shfl(corr, lg * 4 + 1);
      const float cc2 = __shfl(corr, lg * 4 + 2);
      const float cc3 = __shfl(corr, lg * 4 + 3);
#pragma unroll
      for (int dt = 0; dt < 8; ++dt) {
        yacc[dt][0] *= cc0; yacc[dt][1] *= cc1;
        yacc[dt][2] *= cc2; yacc[dt][3] *= cc3;
      }
#pragma unroll
      for (int k2 = 0; k2 < 4; ++k2)
#pragma unroll
        for (int r = 0; r < 4; ++r) st[k2][r] -= d;
    }
    float psum = 0.f;
#pragma unroll
    for (int k2 = 0; k2 < 4; ++k2) {
      const float pe0 = exp2a(st[k2][0]);
      const float pe1 = exp2a(st[k2][1]);
      const float pe2 = exp2a(st[k2][2]);
      const float pe3 = exp2a(st[k2][3]);
      psum += (pe0 + pe1) + (pe2 + pe3);
      uint_t d0, d1;
      asm("v_cvt_pk_bf16_f32 %0, %1, %2" : "=v"(d0) : "v"(pe0), "v"(pe1));
      asm("v_cvt_pk_bf16_f32 %0, %1, %2" : "=v"(d1) : "v"(pe2), "v"(pe3));
      uint2 pkv; pkv.x = d0; pkv.y = d1;
      *(uint2*)&Pl[w][lr][k2 * 16 + lg * 4] = pkv;
    }
    l_p += psum;
    asm volatile("s_waitcnt lgkmcnt(0)" ::: "memory");   // P writes visible in-wave

    // PV: vf direct from L2-resident Vt
    const ushort_t* vtp = vgp + (long)t * 64;
#pragma unroll
    for (int kc = 0; kc < 2; ++kc) {
      const short8 pf = *(const short8*)&Pl[w][lr][kc * 32 + lg * 8];
#pragma unroll
      for (int dt = 0; dt < 8; ++dt) {
        const short8 vf = *(const short8*)(vtp + (long)dt * 16384 + kc * 32);
        yacc[dt] = mfma16(pf, vf, yacc[dt]);
      }
    }
    cfence();
  }

  float l_s = l_p;
  l_s += __shfl_xor(l_s, 16);
  l_s += __shfl_xor(l_s, 32);
  const float linv = 1.f / l_s;
  const float i0 = __shfl(linv, lg * 4 + 0);
  const float i1 = __shfl(linv, lg * 4 + 1);
  const float i2 = __shfl(linv, lg * 4 + 2);
  const float i3 = __shfl(linv, lg * 4 + 3);
  ushort_t* yp = Y + ((long)(b * 1024 + qrow)) * 2048 + h * 128 + lr;
#pragma unroll
  for (int dt = 0; dt < 8; ++dt) {
    yp[(long)(lg * 4 + 0) * 2048 + dt * 16] = f2bf(yacc[dt][0] * i0);
    yp[(long)(lg * 4 + 1) * 2048 + dt * 16] = f2bf(yacc[dt][1] * i1);
    yp[(long)(lg * 4 + 2) * 2048 + dt * 16] = f2bf(yacc[dt][2] * i2);
    yp[(long)(lg * 4 + 3) * 2048 + dt * 16] = f2bf(yacc[dt][3] * i3);
  }
}

// ---------------- launch ----------------
extern "C" void kernel_launch(void* const* d_in, const int* in_sizes, int n_in,
                              void* d_out, int out_size, void* d_ws, size_t ws_size,
                              hipStream_t stream)
{
  (void)in_sizes; (void)n_in; (void)out_size;
  const float* x   = (const float*)d_in[0];
  const float* Wq  = (const float*)d_in[1];
  const float* bq  = (const float*)d_in[2];
  const float* Wkv = (const float*)d_in[3];
  const float* bkv = (const float*)d_in[4];
  const float* Wo  = (const float*)d_in[5];
  const float* bo  = (const float*)d_in[6];
  float* out = (float*)d_out;
  char* ws = (char*)d_ws;

  if (ws_size < 104857600) return;  // need 100 MB

  ushort_t* xb   = (ushort_t*)(ws);              // 32MB; reused as Y after KV GEMM
  ushort_t* Qb   = (ushort_t*)(ws + 33554432);   // 32MB
  ushort_t* KVb  = (ushort_t*)(ws + 67108864);   // 16MB
  ushort_t* Wqb  = (ushort_t*)(ws + 83886080);   // 8MB; reused as Vt after Q GEMM
  ushort_t* Wkvb = (ushort_t*)(ws + 92274688);   // 4MB
  ushort_t* Wob  = (ushort_t*)(ws + 96468992);   // 8MB
  ushort_t* Vtb  = Wqb;
  ushort_t* Yb   = xb;

  k_f2bf4<<<dim3(13312), 256, 0, stream>>>(x, Wq, Wkv, Wo, xb, Wqb, Wkvb, Wob);

  // Q scale = 1/sqrt(128) * log2(e)  (attn softmax runs in exp2 domain)
  const float scale = 0.12751743f;
  k_gemm4<1><<<dim3(256), 1024, 0, stream>>>(xb, Wqb, bq, Qb, 2048, 2048, 8, scale);
  k_gemmkv<<<dim3(8, 64), 256, 0, stream>>>(xb, Wkvb, bkv, KVb, Vtb, 1024, 2048);
  k_attn<<<dim3(2048), 256, 0, stream>>>(Qb, KVb, Vtb, Yb);
  k_gemm4<0><<<dim3(256), 1024, 0, stream>>>(Yb, Wob, bo, out, 2048, 2048, 8, 1.0f);
}

// Round 18
// 299.129 us; speedup vs baseline: 1.3611x; 1.3611x over previous
//
#include <hip/hip_runtime.h>

typedef short short8 __attribute__((ext_vector_type(8)));
typedef short short4v __attribute__((ext_vector_type(4)));
typedef float floatx4 __attribute__((ext_vector_type(4)));
typedef unsigned short ushort_t;
typedef unsigned int uint_t;

#define DI __device__ __forceinline__

DI ushort_t f2bf(float f) {
  uint_t u = __builtin_bit_cast(uint_t, f);
  uint_t r = u + 0x7FFFu + ((u >> 16) & 1u);
  return (ushort_t)(r >> 16);
}

DI float exp2a(float x) {            // v_exp_f32 IS 2^x on AMD
  float r;
  asm("v_exp_f32 %0, %1" : "=v"(r) : "v"(x));
  return r;
}

DI floatx4 mfma16(short8 a, short8 b, floatx4 c) {
  return __builtin_amdgcn_mfma_f32_16x16x32_bf16(a, b, c, 0, 0, 0);
}

DI void async16(const void* g, void* l) {
  __builtin_amdgcn_global_load_lds(
      (__attribute__((address_space(1))) void*)(g),
      (__attribute__((address_space(3))) void*)(l), 16, 0, 0);
}

DI void cfence() { asm volatile("" ::: "memory"); }

// ---------------- fused f32 -> bf16 conversion (4 segments, 1 launch) ----------------
__global__ __launch_bounds__(256)
void k_f2bf4(const float* __restrict__ x, const float* __restrict__ wq,
             const float* __restrict__ wkv, const float* __restrict__ wo,
             ushort_t* __restrict__ xb, ushort_t* __restrict__ wqb,
             ushort_t* __restrict__ wkvb, ushort_t* __restrict__ wob)
{
  const int blk = blockIdx.x;
  const float* in; ushort_t* out; long base;
  if (blk < 8192)       { in = x;   out = xb;   base = (long)blk * 2048; }
  else if (blk < 10240) { in = wq;  out = wqb;  base = (long)(blk - 8192) * 2048; }
  else if (blk < 11264) { in = wkv; out = wkvb; base = (long)(blk - 10240) * 2048; }
  else                  { in = wo;  out = wob;  base = (long)(blk - 11264) * 2048; }
  const long i = base + (long)threadIdx.x * 8;
  const float4 a = *(const float4*)(in + i);
  const float4 b = *(const float4*)(in + i + 4);
  union { short8 s; ushort_t u[8]; } o;
  o.u[0] = f2bf(a.x); o.u[1] = f2bf(a.y); o.u[2] = f2bf(a.z); o.u[3] = f2bf(a.w);
  o.u[4] = f2bf(b.x); o.u[5] = f2bf(b.y); o.u[6] = f2bf(b.z); o.u[7] = f2bf(b.w);
  *(short8*)(out + i) = o.s;
}

// ======== 128x128 quad-buffered KV GEMM + fused V-transpose epilogue (r13-proven) ========
__global__ __launch_bounds__(256)
void k_gemmkv(const ushort_t* __restrict__ A, const ushort_t* __restrict__ B,
              const float* __restrict__ bias, ushort_t* __restrict__ KVout,
              ushort_t* __restrict__ Vt, int N, int K)
{
  __shared__ __align__(16) ushort_t As[4][128 * 32];
  __shared__ __align__(16) ushort_t Bs[4][128 * 32];
  const int tid = threadIdx.x;
  const int w = tid >> 6, l = tid & 63;
  const int wm = w >> 1, wn = w & 1;
  const int lr = l & 15, lg = l >> 4;
  const long m0 = (long)blockIdx.y * 128;
  const long n0 = (long)blockIdx.x * 128;

  const floatx4 fz = {0.f, 0.f, 0.f, 0.f};
  floatx4 acc[4][4];
#pragma unroll
  for (int i = 0; i < 4; ++i)
#pragma unroll
    for (int j = 0; j < 4; ++j) acc[i][j] = fz;

  const int c0 = tid, c1 = 256 + tid;
  const int r0 = c0 >> 2, r1 = c1 >> 2;
  const ushort_t* gA0 = A + (m0 + r0) * K + (((c0 & 3) ^ (r0 & 3)) << 3);
  const ushort_t* gA1 = A + (m0 + r1) * K + (((c1 & 3) ^ (r1 & 3)) << 3);
  const ushort_t* gB0 = B + (n0 + r0) * K + (((c0 & 3) ^ (r0 & 3)) << 3);
  const ushort_t* gB1 = B + (n0 + r1) * K + (((c1 & 3) ^ (r1 & 3)) << 3);

  const int nK = K >> 5;
#pragma unroll
  for (int pt = 0; pt < 3; ++pt) {
    const int ko = pt << 5;
    async16(gA0 + ko, &As[pt][c0 * 8]);
    async16(gA1 + ko, &As[pt][c1 * 8]);
    async16(gB0 + ko, &Bs[pt][c0 * 8]);
    async16(gB1 + ko, &Bs[pt][c1 * 8]);
  }

  const int xg = (lr & 3);

  for (int kt = 0; kt < nK; ++kt) {
    const int cur = kt & 3;
    const int rem = nK - 1 - kt;
    if (rem >= 3) {
      const int ko = (kt + 3) << 5;
      const int nb = (kt + 3) & 3;
      async16(gA0 + ko, &As[nb][c0 * 8]);
      async16(gA1 + ko, &As[nb][c1 * 8]);
      async16(gB0 + ko, &Bs[nb][c0 * 8]);
      async16(gB1 + ko, &Bs[nb][c1 * 8]);
      asm volatile("s_waitcnt vmcnt(12)" ::: "memory");
    } else if (rem == 2) {
      asm volatile("s_waitcnt vmcnt(8)" ::: "memory");
    } else if (rem == 1) {
      asm volatile("s_waitcnt vmcnt(4)" ::: "memory");
    } else {
      asm volatile("s_waitcnt vmcnt(0)" ::: "memory");
    }
    __builtin_amdgcn_s_barrier();
    cfence();

    short8 a[4], b[4];
#pragma unroll
    for (int i = 0; i < 4; ++i)
      a[i] = *(const short8*)&As[cur][(wm * 64 + i * 16 + lr) * 32 + ((lg ^ xg) * 8)];
#pragma unroll
    for (int j = 0; j < 4; ++j)
      b[j] = *(const short8*)&Bs[cur][(wn * 64 + j * 16 + lr) * 32 + ((lg ^ xg) * 8)];
#pragma unroll
    for (int i = 0; i < 4; ++i)
#pragma unroll
      for (int j = 0; j < 4; ++j)
        acc[i][j] = mfma16(a[i], b[j], acc[i][j]);

    asm volatile("s_waitcnt lgkmcnt(0)" ::: "memory");
    __builtin_amdgcn_s_barrier();
    cfence();
  }

#pragma unroll
  for (int j = 0; j < 4; ++j) {
    const long gn = n0 + wn * 64 + j * 16 + lr;
    const float bv = bias[gn];
    const int isV = (int)((gn >> 7) & 1);
    const long vrowB = (long)((gn >> 8) * 128 + (gn & 127)) * 1024;
#pragma unroll
    for (int i = 0; i < 4; ++i) {
      const long gm = m0 + wm * 64 + i * 16 + lg * 4;
#pragma unroll
      for (int r = 0; r < 4; ++r) {
        const ushort_t ov = f2bf(acc[i][j][r] + bv);
        const long gmr = gm + r;
        if (isV) Vt[((gmr >> 10) * 512) * 1024 + vrowB + (gmr & 1023)] = ov;
        else     KVout[gmr * 1024 + gn] = ov;
      }
    }
  }
}

// ======== 256x256 GEMM, 16 waves, 4 waves/SIMD (r16, best measured) — Q and O ========
template<int OUT_BF16>
__global__ __launch_bounds__(1024, 4)
void k_gemm4(const ushort_t* __restrict__ A, const ushort_t* __restrict__ B,
             const float* __restrict__ bias, void* __restrict__ Cout,
             int N, int K, int gx, float out_scale)
{
  __shared__ __align__(16) ushort_t Al[2][256 * 64];
  __shared__ __align__(16) ushort_t Bl[2][256 * 64];
  const int tid = threadIdx.x;
  const int w = tid >> 6, l = tid & 63;
  const int wrow = w >> 2, wcol = w & 3;
  const int lr = l & 15, lg = l >> 4;

  const int nwg = gridDim.x;
  const int qd = nwg >> 3;
  const int p = blockIdx.x;
  const int swz = (p & 7) * qd + (p >> 3);
  const long m0 = (long)(swz / gx) * 256;
  const long n0 = (long)(swz % gx) * 256;

  const floatx4 fz = {0.f, 0.f, 0.f, 0.f};
  floatx4 acc[4][4];
#pragma unroll
  for (int i = 0; i < 4; ++i)
#pragma unroll
    for (int j = 0; j < 4; ++j) acc[i][j] = fz;

  const int cA0 = tid, cA1 = 1024 + tid;
  const int rA0 = cA0 >> 3, rA1 = cA1 >> 3;
  const ushort_t* aS0 = A + (m0 + rA0) * K + (((cA0 & 7) ^ (rA0 & 7)) << 3);
  const ushort_t* aS1 = A + (m0 + rA1) * K + (((cA1 & 7) ^ (rA1 & 7)) << 3);
  const ushort_t* bS0 = B + (n0 + rA0) * K + (((cA0 & 7) ^ (rA0 & 7)) << 3);
  const ushort_t* bS1 = B + (n0 + rA1) * K + (((cA1 & 7) ^ (rA1 & 7)) << 3);
  const int d0 = cA0 * 8, d1 = cA1 * 8;

  const int x8 = lr & 7;
  const int g0 = (lg ^ x8) * 8;
  const int g1 = ((4 + lg) ^ x8) * 8;
  const int raB = (wrow * 64 + lr) * 64;
  const int rbB = (wcol * 64 + lr) * 64;

  const int nT = K >> 6;
  async16(aS0, &Al[0][d0]);
  async16(aS1, &Al[0][d1]);
  async16(bS0, &Bl[0][d0]);
  async16(bS1, &Bl[0][d1]);

  for (int t = 0; t < nT; ++t) {
    const int cur = t & 1;
    asm volatile("s_waitcnt vmcnt(0) lgkmcnt(0)" ::: "memory");
    __builtin_amdgcn_s_barrier();
    cfence();
    if (t + 1 < nT) {
      const int ko = (t + 1) << 6;
      async16(aS0 + ko, &Al[cur ^ 1][d0]);
      async16(aS1 + ko, &Al[cur ^ 1][d1]);
      async16(bS0 + ko, &Bl[cur ^ 1][d0]);
      async16(bS1 + ko, &Bl[cur ^ 1][d1]);
    }
    short8 a[4], b[4];
#pragma unroll
    for (int i = 0; i < 4; ++i)
      a[i] = *(const short8*)&Al[cur][raB + i * 1024 + g0];
#pragma unroll
    for (int j = 0; j < 4; ++j)
      b[j] = *(const short8*)&Bl[cur][rbB + j * 1024 + g0];
    __builtin_amdgcn_s_setprio(1);
#pragma unroll
    for (int i = 0; i < 4; ++i)
#pragma unroll
      for (int j = 0; j < 4; ++j)
        acc[i][j] = mfma16(a[i], b[j], acc[i][j]);
    __builtin_amdgcn_s_setprio(0);
#pragma unroll
    for (int i = 0; i < 4; ++i)
      a[i] = *(const short8*)&Al[cur][raB + i * 1024 + g1];
#pragma unroll
    for (int j = 0; j < 4; ++j)
      b[j] = *(const short8*)&Bl[cur][rbB + j * 1024 + g1];
    __builtin_amdgcn_s_setprio(1);
#pragma unroll
    for (int i = 0; i < 4; ++i)
#pragma unroll
      for (int j = 0; j < 4; ++j)
        acc[i][j] = mfma16(a[i], b[j], acc[i][j]);
    __builtin_amdgcn_s_setprio(0);
    cfence();
  }

#pragma unroll
  for (int j = 0; j < 4; ++j) {
    const long gn = n0 + wcol * 64 + j * 16 + lr;
    const float bv = bias[gn];
#pragma unroll
    for (int i = 0; i < 4; ++i) {
      const long gm = m0 + wrow * 64 + i * 16 + lg * 4;
#pragma unroll
      for (int r = 0; r < 4; ++r) {
        const float v = (acc[i][j][r] + bv) * out_scale;
        if (OUT_BF16) ((ushort_t*)Cout)[(gm + r) * N + gn] = f2bf(v);
        else          ((float*)Cout)[(gm + r) * N + gn] = v;
      }
    }
  }
}

// ---------------- Flash attention (causal, GQA) — r15/r16-proven ----------------
__global__ __launch_bounds__(256)
void k_attn(const ushort_t* __restrict__ Q, const ushort_t* __restrict__ KV,
            const ushort_t* __restrict__ Vt, ushort_t* __restrict__ Y)
{
  __shared__ __align__(16) ushort_t Kl[2][64 * 128];
  __shared__ __align__(16) ushort_t Vl[2][128 * 64];
  __shared__ __align__(16) ushort_t Pl[4][16][72];
  const int tid = threadIdx.x;
  const int w = tid >> 6, l = tid & 63;
  const int lr = l & 15, lg = l >> 4;
  const int p = blockIdx.x;
  const int v = ((p & 7) << 8) | (p >> 3);
  const int b = v >> 8;
  const int kh = (v >> 6) & 3;
  const int hs = (v >> 4) & 3;
  const int qt = 15 - (v & 15);
  const int h = kh * 4 + hs;
  const int qrow = qt * 64 + w * 16;

  const ushort_t* qptr = Q + ((long)(b * 1024 + qrow + lr)) * 2048 + h * 128 + lg * 8;
  short8 qf[4];
#pragma unroll
  for (int c = 0; c < 4; ++c) qf[c] = *(const short8*)(qptr + c * 32);

  const ushort_t* kg[4];
  const ushort_t* vg[4];
  int ld[4];
#pragma unroll
  for (int i = 0; i < 4; ++i) {
    const int c = i * 256 + tid;
    const int row = c >> 4, sgk = (c & 15) ^ (row & 7);
    kg[i] = KV + ((long)(b * 1024 + row)) * 1024 + kh * 256 + sgk * 8;
    const int d = c >> 3, sgv = (c & 7) ^ (d & 7);
    vg[i] = Vt + ((long)((b * 4 + kh) * 128 + d)) * 1024 + sgv * 8;
    ld[i] = c * 8;
  }

  float m_s = 0.f;          // reference max (0-init safe: defer-max bounds P by 2^8)
  float l_p = 0.f;          // per-lane partial denominator
  const floatx4 fz = {0.f, 0.f, 0.f, 0.f};
  floatx4 yacc[8];
#pragma unroll
  for (int dt = 0; dt < 8; ++dt) yacc[dt] = fz;

  const int xk = (lr & 7) << 4;

#pragma unroll
  for (int i = 0; i < 4; ++i) async16(kg[i], &Kl[0][ld[i]]);
#pragma unroll
  for (int i = 0; i < 4; ++i) async16(vg[i], &Vl[0][ld[i]]);

  for (int t = 0; t <= qt; ++t) {
    const ushort_t* KlC = &Kl[t & 1][0];
    const ushort_t* VlC = &Vl[t & 1][0];
    asm volatile("s_waitcnt vmcnt(0) lgkmcnt(0)" ::: "memory");
    __builtin_amdgcn_s_barrier();
    cfence();
    if (t < qt) {
      const long ko = (long)(t + 1) * 65536;
      const long vo = (long)(t + 1) * 64;
      ushort_t* KlN = &Kl[(t + 1) & 1][0];
      ushort_t* VlN = &Vl[(t + 1) & 1][0];
#pragma unroll
      for (int i = 0; i < 4; ++i) async16(kg[i] + ko, &KlN[ld[i]]);
#pragma unroll
      for (int i = 0; i < 4; ++i) async16(vg[i] + vo, &VlN[ld[i]]);
    }

    const floatx4 finit = {-m_s, -m_s, -m_s, -m_s};
    floatx4 st[4];
#pragma unroll
    for (int k2 = 0; k2 < 4; ++k2) {
      floatx4 sacc = finit;
      const int row = k2 * 16 + lr;
#pragma unroll
      for (int c = 0; c < 4; ++c) {
        const int off = row * 256 + ((c * 64 + lg * 16) ^ xk);
        const short8 kf = *(const short8*)((const char*)KlC + off);
        sacc = mfma16(kf, qf[c], sacc);
      }
      st[k2] = sacc;
    }
    if (t == qt) {
      const int qg = qrow + lr;
#pragma unroll
      for (int k2 = 0; k2 < 4; ++k2)
#pragma unroll
        for (int r = 0; r < 4; ++r)
          if (t * 64 + k2 * 16 + lg * 4 + r > qg) st[k2][r] = -__builtin_inff();
    }
    float pm = -__builtin_inff();
#pragma unroll
    for (int k2 = 0; k2 < 4; ++k2)
      pm = fmaxf(pm, fmaxf(fmaxf(st[k2][0], st[k2][1]), fmaxf(st[k2][2], st[k2][3])));
    if (!__all(pm <= 8.f)) {
      float pmf = fmaxf(pm, __shfl_xor(pm, 16));
      pmf = fmaxf(pmf, __shfl_xor(pmf, 32));
      const float d = fmaxf(pmf, 0.f);
      m_s += d;
      const float corr = exp2a(-d);
      l_p *= corr;
      const float cc0 = __shfl(corr, lg * 4 + 0);
      const float cc1 = __shfl(corr, lg * 4 + 1);
      const float cc2 = __shfl(corr, lg * 4 + 2);
      const float cc3 = __shfl(corr, lg * 4 + 3);
#pragma unroll
      for (int dt = 0; dt < 8; ++dt) {
        yacc[dt][0] *= cc0; yacc[dt][1] *= cc1;
        yacc[dt][2] *= cc2; yacc[dt][3] *= cc3;
      }
#pragma unroll
      for (int k2 = 0; k2 < 4; ++k2)
#pragma unroll
        for (int r = 0; r < 4; ++r) st[k2][r] -= d;
    }
    float psum = 0.f;
#pragma unroll
    for (int k2 = 0; k2 < 4; ++k2) {
      const float pe0 = exp2a(st[k2][0]);
      const float pe1 = exp2a(st[k2][1]);
      const float pe2 = exp2a(st[k2][2]);
      const float pe3 = exp2a(st[k2][3]);
      psum += (pe0 + pe1) + (pe2 + pe3);
      uint_t d0, d1;
      asm("v_cvt_pk_bf16_f32 %0, %1, %2" : "=v"(d0) : "v"(pe0), "v"(pe1));
      asm("v_cvt_pk_bf16_f32 %0, %1, %2" : "=v"(d1) : "v"(pe2), "v"(pe3));
      uint2 pkv; pkv.x = d0; pkv.y = d1;
      *(uint2*)&Pl[w][lr][k2 * 16 + lg * 4] = pkv;
    }
    l_p += psum;
    asm volatile("s_waitcnt lgkmcnt(0)" ::: "memory");

#pragma unroll
    for (int kc = 0; kc < 2; ++kc) {
      const short8 pf = *(const short8*)&Pl[w][lr][kc * 32 + lg * 8];
#pragma unroll
      for (int dt = 0; dt < 8; ++dt) {
        const int d = dt * 16 + lr;
        const int off = d * 128 + ((kc * 64 + lg * 16) ^ xk);
        const short8 vf = *(const short8*)((const char*)VlC + off);
        yacc[dt] = mfma16(pf, vf, yacc[dt]);
      }
    }
    cfence();
  }

  float l_s = l_p;
  l_s += __shfl_xor(l_s, 16);
  l_s += __shfl_xor(l_s, 32);
  const float linv = 1.f / l_s;
  const float i0 = __shfl(linv, lg * 4 + 0);
  const float i1 = __shfl(linv, lg * 4 + 1);
  const float i2 = __shfl(linv, lg * 4 + 2);
  const float i3 = __shfl(linv, lg * 4 + 3);
  ushort_t* yp = Y + ((long)(b * 1024 + qrow)) * 2048 + h * 128 + lr;
#pragma unroll
  for (int dt = 0; dt < 8; ++dt) {
    yp[(long)(lg * 4 + 0) * 2048 + dt * 16] = f2bf(yacc[dt][0] * i0);
    yp[(long)(lg * 4 + 1) * 2048 + dt * 16] = f2bf(yacc[dt][1] * i1);
    yp[(long)(lg * 4 + 2) * 2048 + dt * 16] = f2bf(yacc[dt][2] * i2);
    yp[(long)(lg * 4 + 3) * 2048 + dt * 16] = f2bf(yacc[dt][3] * i3);
  }
}

// ---------------- launch ----------------
extern "C" void kernel_launch(void* const* d_in, const int* in_sizes, int n_in,
                              void* d_out, int out_size, void* d_ws, size_t ws_size,
                              hipStream_t stream)
{
  (void)in_sizes; (void)n_in; (void)out_size;
  const float* x   = (const float*)d_in[0];
  const float* Wq  = (const float*)d_in[1];
  const float* bq  = (const float*)d_in[2];
  const float* Wkv = (const float*)d_in[3];
  const float* bkv = (const float*)d_in[4];
  const float* Wo  = (const float*)d_in[5];
  const float* bo  = (const float*)d_in[6];
  float* out = (float*)d_out;
  char* ws = (char*)d_ws;

  if (ws_size < 104857600) return;  // need 100 MB

  ushort_t* xb   = (ushort_t*)(ws);              // 32MB; reused as Y after KV GEMM
  ushort_t* Qb   = (ushort_t*)(ws + 33554432);   // 32MB
  ushort_t* KVb  = (ushort_t*)(ws + 67108864);   // 16MB
  ushort_t* Wqb  = (ushort_t*)(ws + 83886080);   // 8MB; reused as Vt after Q GEMM
  ushort_t* Wkvb = (ushort_t*)(ws + 92274688);   // 4MB
  ushort_t* Wob  = (ushort_t*)(ws + 96468992);   // 8MB
  ushort_t* Vtb  = Wqb;
  ushort_t* Yb   = xb;

  k_f2bf4<<<dim3(13312), 256, 0, stream>>>(x, Wq, Wkv, Wo, xb, Wqb, Wkvb, Wob);

  // Q scale = 1/sqrt(128) * log2(e)  (attn softmax runs in exp2 domain)
  const float scale = 0.12751743f;
  k_gemm4<1><<<dim3(256), 1024, 0, stream>>>(xb, Wqb, bq, Qb, 2048, 2048, 8, scale);
  k_gemmkv<<<dim3(8, 64), 256, 0, stream>>>(xb, Wkvb, bkv, KVb, Vtb, 1024, 2048);
  k_attn<<<dim3(2048), 256, 0, stream>>>(Qb, KVb, Vtb, Yb);
  k_gemm4<0><<<dim3(256), 1024, 0, stream>>>(Yb, Wob, bo, out, 2048, 2048, 8, 1.0f);
}